// Round 7
// baseline (1402.473 us; speedup 1.0000x reference)
//
#include <hip/hip_runtime.h>
#include <hip/hip_bf16.h>
#include <math.h>

#define B_    16
#define LQ_   900
#define D_    256
#define NH_   8
#define HD_   32
#define NL_   4
#define NP_   4
#define DFFN_ 2048
#define LIN_  21760

typedef unsigned short u16;
typedef __attribute__((ext_vector_type(8))) short bf16x8;
typedef __attribute__((ext_vector_type(4))) float f32x4;

__device__ __forceinline__ short f2bf(float f) {
    unsigned u = __float_as_uint(f);
    u += 0x7fffu + ((u >> 16) & 1u);   // RNE
    return (short)(u >> 16);
}
__device__ __forceinline__ float bf2f(u16 u) {
    return __uint_as_float(((unsigned)u) << 16);
}

// ---------------------------------------------------------------------------
// weight prep: fp32 weights -> bf16 Wb (samp & attw placed ADJACENT for fusion)
// ---------------------------------------------------------------------------
#define WOFF_INPROJ  0
#define WOFF_OUTPROJ 196608
#define WOFF_VALPROJ 262144
#define WOFF_SAMP    327680
#define WOFF_ATTW    393216
#define WOFF_MSOUT   425984
#define WOFF_FFN1    491520
#define WOFF_FFN2    1015808
#define WTOTAL       1540096

__global__ __launch_bounds__(256) void wprep_kernel(const float* __restrict__ s0,
                                                    const float* __restrict__ s1,
                                                    const float* __restrict__ s2,
                                                    const float* __restrict__ s3,
                                                    const float* __restrict__ s4,
                                                    const float* __restrict__ s5,
                                                    const float* __restrict__ s6,
                                                    const float* __restrict__ s7,
                                                    u16* __restrict__ Wb) {
    int i8 = (blockIdx.x * 256 + threadIdx.x) * 8;
    if (i8 >= WTOTAL) return;
    const float* src; int rel;
    if      (i8 < WOFF_OUTPROJ) { src = s0; rel = i8; }
    else if (i8 < WOFF_VALPROJ) { src = s1; rel = i8 - WOFF_OUTPROJ; }
    else if (i8 < WOFF_SAMP)    { src = s2; rel = i8 - WOFF_VALPROJ; }
    else if (i8 < WOFF_ATTW)    { src = s3; rel = i8 - WOFF_SAMP; }
    else if (i8 < WOFF_MSOUT)   { src = s4; rel = i8 - WOFF_ATTW; }
    else if (i8 < WOFF_FFN1)    { src = s5; rel = i8 - WOFF_MSOUT; }
    else if (i8 < WOFF_FFN2)    { src = s6; rel = i8 - WOFF_FFN1; }
    else                        { src = s7; rel = i8 - WOFF_FFN2; }
    float4 v0 = *(const float4*)(src + rel);
    float4 v1 = *(const float4*)(src + rel + 4);
    short o[8];
    o[0] = f2bf(v0.x); o[1] = f2bf(v0.y); o[2] = f2bf(v0.z); o[3] = f2bf(v0.w);
    o[4] = f2bf(v1.x); o[5] = f2bf(v1.y); o[6] = f2bf(v1.z); o[7] = f2bf(v1.w);
    *(bf16x8*)(Wb + i8) = *(bf16x8*)o;
}

// bias concat (f32): [inproj768][outproj256][valproj256][samp256][attw128][msout256][ffn1 2048][ffn2 256]
#define BOFF_INPROJ  0
#define BOFF_OUTPROJ 768
#define BOFF_VALPROJ 1024
#define BOFF_SAMPATT 1280
#define BOFF_MSOUT   1664
#define BOFF_FFN1    1920
#define BOFF_FFN2    3968
#define BTOTAL       4224

__global__ __launch_bounds__(256) void bprep_kernel(const float* __restrict__ b0,
                                                    const float* __restrict__ b1,
                                                    const float* __restrict__ b2,
                                                    const float* __restrict__ b3,
                                                    const float* __restrict__ b4,
                                                    const float* __restrict__ b5,
                                                    const float* __restrict__ b6,
                                                    const float* __restrict__ b7,
                                                    float* __restrict__ Bb) {
    int i = blockIdx.x * 256 + threadIdx.x;
    if (i >= BTOTAL) return;
    const float* s; int rel;
    if      (i < BOFF_OUTPROJ) { s = b0; rel = i; }
    else if (i < BOFF_VALPROJ) { s = b1; rel = i - BOFF_OUTPROJ; }
    else if (i < BOFF_SAMPATT) { s = b2; rel = i - BOFF_VALPROJ; }
    else if (i < 1536)         { s = b3; rel = i - BOFF_SAMPATT; }
    else if (i < BOFF_MSOUT)   { s = b4; rel = i - 1536; }
    else if (i < BOFF_FFN1)    { s = b5; rel = i - BOFF_MSOUT; }
    else if (i < BOFF_FFN2)    { s = b6; rel = i - BOFF_FFN1; }
    else                       { s = b7; rel = i - BOFF_FFN2; }
    Bb[i] = s[rel];
}

// ---------------------------------------------------------------------------
// fused add -> bf16 (and optional bf16 copy of input a)
// ---------------------------------------------------------------------------
__global__ __launch_bounds__(256) void add_bf16_kernel(const float* __restrict__ a,
                                                       const float* __restrict__ b,
                                                       u16* __restrict__ osum,
                                                       u16* __restrict__ oa,
                                                       size_t n4) {
    size_t i = (size_t)blockIdx.x * blockDim.x + threadIdx.x;
    if (i >= n4) return;
    float4 x = ((const float4*)a)[i];
    float4 y = ((const float4*)b)[i];
    ushort4 s;
    s.x = (u16)f2bf(x.x + y.x); s.y = (u16)f2bf(x.y + y.y);
    s.z = (u16)f2bf(x.z + y.z); s.w = (u16)f2bf(x.w + y.w);
    ((ushort4*)osum)[i] = s;
    if (oa) {
        ushort4 q;
        q.x = (u16)f2bf(x.x); q.y = (u16)f2bf(x.y);
        q.z = (u16)f2bf(x.z); q.w = (u16)f2bf(x.w);
        ((ushort4*)oa)[i] = q;
    }
}

// ---------------------------------------------------------------------------
// weight-stationary GEMM, K=256 fixed: C[M,N] = A @ W[N,256]^T + bias (+res)(+relu)
// One wave owns 32 output cols (2 j-tiles) for CH m-tiles of 16 rows.
// W frags live in 64 VGPR for the wave's lifetime. NO LDS, NO barriers:
// waves slip freely -> HBM latency hidden by TLP; bf16-A path is 2-deep
// register-pipelined (p/q sets, static indexing).
// M must be a multiple of 16; N a multiple of 32.
// ---------------------------------------------------------------------------
template <typename TA, typename TC>
__global__ __launch_bounds__(256) void wsgemm_kernel(const TA* __restrict__ A,
                                                     const u16* __restrict__ W,
                                                     const float* __restrict__ bias,
                                                     const float* __restrict__ res,
                                                     TC* __restrict__ C,
                                                     int MT, int NS, int CH, int N, int relu) {
    const int lane = threadIdx.x & 63;
    const int l15  = lane & 15;
    const int g    = lane >> 4;
    const int wid  = blockIdx.x * 4 + (threadIdx.x >> 6);
    const int nchunks = (MT + CH - 1) / CH;
    if (wid >= NS * nchunks) return;
    const int ns = wid % NS;
    const int n0 = ns * 32;
    int mt = (wid / NS) * CH;
    const int mtend = (mt + CH < MT) ? mt + CH : MT;

    // W fragments: w[j][ks] = W[(n0+j*16+l15)][ks*32 + g*8 ..+7]
    bf16x8 w0[8], w1[8];
    {
        const u16* wp0 = W + (size_t)(n0 + l15) * 256 + g * 8;
        const u16* wp1 = W + (size_t)(n0 + 16 + l15) * 256 + g * 8;
        #pragma unroll
        for (int ks = 0; ks < 8; ++ks) {
            w0[ks] = *(const bf16x8*)(wp0 + ks * 32);
            w1[ks] = *(const bf16x8*)(wp1 + ks * 32);
        }
    }
    const float bn0 = bias[n0 + l15];
    const float bn1 = bias[n0 + 16 + l15];

    auto compute_store = [&](const bf16x8 (&a)[8], int m0) {
        f32x4 acc0 = {0.f, 0.f, 0.f, 0.f}, acc1 = {0.f, 0.f, 0.f, 0.f};
        #pragma unroll
        for (int ks = 0; ks < 8; ++ks) {
            acc0 = __builtin_amdgcn_mfma_f32_16x16x32_bf16(a[ks], w0[ks], acc0, 0, 0, 0);
            acc1 = __builtin_amdgcn_mfma_f32_16x16x32_bf16(a[ks], w1[ks], acc1, 0, 0, 0);
        }
        // D layout: col = l15 (n), row = g*4 + r (m)  [m89-verified]
        #pragma unroll
        for (int r = 0; r < 4; ++r) {
            const int m = m0 + g * 4 + r;
            float v0 = acc0[r] + bn0;
            float v1 = acc1[r] + bn1;
            if (res) {
                v0 += res[(size_t)m * N + n0 + l15];
                v1 += res[(size_t)m * N + n0 + 16 + l15];
            }
            if (relu) { v0 = fmaxf(v0, 0.f); v1 = fmaxf(v1, 0.f); }
            if constexpr (sizeof(TC) == 4) {
                C[(size_t)m * N + n0 + l15]      = v0;
                C[(size_t)m * N + n0 + 16 + l15] = v1;
            } else {
                C[(size_t)m * N + n0 + l15]      = (TC)(u16)f2bf(v0);
                C[(size_t)m * N + n0 + 16 + l15] = (TC)(u16)f2bf(v1);
            }
        }
    };

    if constexpr (sizeof(TA) == 2) {
        const u16* Ab = (const u16*)A;
        bf16x8 p[8], q[8];
        {
            const u16* ar = Ab + (size_t)(mt * 16 + l15) * 256 + g * 8;
            #pragma unroll
            for (int ks = 0; ks < 8; ++ks) p[ks] = *(const bf16x8*)(ar + ks * 32);
        }
        while (true) {
            if (mt + 1 < mtend) {
                const u16* ar = Ab + (size_t)((mt + 1) * 16 + l15) * 256 + g * 8;
                #pragma unroll
                for (int ks = 0; ks < 8; ++ks) q[ks] = *(const bf16x8*)(ar + ks * 32);
            }
            compute_store(p, mt * 16);
            if (++mt >= mtend) break;
            if (mt + 1 < mtend) {
                const u16* ar = Ab + (size_t)((mt + 1) * 16 + l15) * 256 + g * 8;
                #pragma unroll
                for (int ks = 0; ks < 8; ++ks) p[ks] = *(const bf16x8*)(ar + ks * 32);
            }
            compute_store(q, mt * 16);
            if (++mt >= mtend) break;
        }
    } else {
        const float* Af = (const float*)A;
        for (; mt < mtend; ++mt) {
            const float* ar = Af + (size_t)(mt * 16 + l15) * 256 + g * 8;
            float4 f0[8], f1[8];
            #pragma unroll
            for (int ks = 0; ks < 8; ++ks) {
                f0[ks] = *(const float4*)(ar + ks * 32);
                f1[ks] = *(const float4*)(ar + ks * 32 + 4);
            }
            bf16x8 a[8];
            #pragma unroll
            for (int ks = 0; ks < 8; ++ks) {
                short tmp[8];
                tmp[0] = f2bf(f0[ks].x); tmp[1] = f2bf(f0[ks].y);
                tmp[2] = f2bf(f0[ks].z); tmp[3] = f2bf(f0[ks].w);
                tmp[4] = f2bf(f1[ks].x); tmp[5] = f2bf(f1[ks].y);
                tmp[6] = f2bf(f1[ks].z); tmp[7] = f2bf(f1[ks].w);
                a[ks] = *(bf16x8*)tmp;
            }
            compute_store(a, mt * 16);
        }
    }
}

// ---------------------------------------------------------------------------
// pipelined bf16 MFMA GEMM (kept for FFN2, K=2048): 128x128 tile, BK=32, dbuf
// ---------------------------------------------------------------------------
#define LDK 40
template <typename TA, typename TC>
__global__ __launch_bounds__(256) void gemm2_kernel(const TA* __restrict__ A,
                                                    const u16* __restrict__ W,
                                                    const float* __restrict__ bias,
                                                    const float* __restrict__ res,
                                                    TC* __restrict__ C,
                                                    int M, int N, int K, int relu) {
    __shared__ __align__(16) u16 As[2][128 * LDK];
    __shared__ __align__(16) u16 Bs[2][128 * LDK];

    const int n0 = blockIdx.x * 128;
    const int m0 = blockIdx.y * 128;
    const int t  = threadIdx.x;

    const int srow = t >> 1;
    const int scol = (t & 1) << 4;

    const int lane = t & 63;
    const int lr   = lane & 15;
    const int kg   = lane >> 4;
    const int wid  = t >> 6;
    const int wr   = wid >> 1;
    const int wc   = wid & 1;

    f32x4 acc[4][4] = {};

    const int  nk  = K >> 5;
    const int  gm  = m0 + srow;
    const bool mok = (gm < M);

    const u16* ab16 = (const u16*)A + (size_t)(mok ? gm : 0) * K + scol;
    const u16* wp   = W + (size_t)(n0 + srow) * K + scol;

    bf16x8 ab[2], wf[2];
    if (mok) { ab[0] = *(const bf16x8*)ab16; ab[1] = *(const bf16x8*)(ab16 + 8); }
    else {
        #pragma unroll
        for (int q = 0; q < 8; ++q) { ab[0][q] = 0; ab[1][q] = 0; }
    }
    wf[0] = *(const bf16x8*)wp;
    wf[1] = *(const bf16x8*)(wp + 8);

    for (int kt = 0; kt < nk; ++kt) {
        const int cur = kt & 1;
        *(bf16x8*)&As[cur][srow * LDK + scol]     = ab[0];
        *(bf16x8*)&As[cur][srow * LDK + scol + 8] = ab[1];
        *(bf16x8*)&Bs[cur][srow * LDK + scol]     = wf[0];
        *(bf16x8*)&Bs[cur][srow * LDK + scol + 8] = wf[1];

        if (kt + 1 < nk) {
            const int k1 = (kt + 1) << 5;
            if (mok) {
                ab[0] = *(const bf16x8*)(ab16 + k1);
                ab[1] = *(const bf16x8*)(ab16 + k1 + 8);
            }
            wf[0] = *(const bf16x8*)(wp + k1);
            wf[1] = *(const bf16x8*)(wp + k1 + 8);
        }

        __syncthreads();

        const u16* pA = &As[cur][(wr * 64 + lr) * LDK + kg * 8];
        const u16* pB = &Bs[cur][(wc * 64 + lr) * LDK + kg * 8];
        bf16x8 a[4], b[4];
        #pragma unroll
        for (int i = 0; i < 4; ++i) a[i] = *(const bf16x8*)(pA + i * 16 * LDK);
        #pragma unroll
        for (int j = 0; j < 4; ++j) b[j] = *(const bf16x8*)(pB + j * 16 * LDK);
        #pragma unroll
        for (int i = 0; i < 4; ++i)
            #pragma unroll
            for (int j = 0; j < 4; ++j)
                acc[i][j] = __builtin_amdgcn_mfma_f32_16x16x32_bf16(a[i], b[j], acc[i][j], 0, 0, 0);
    }

    #pragma unroll
    for (int i = 0; i < 4; ++i) {
        #pragma unroll
        for (int j = 0; j < 4; ++j) {
            const int n = n0 + wc * 64 + j * 16 + lr;
            const float bn = bias[n];
            #pragma unroll
            for (int r = 0; r < 4; ++r) {
                const int m = m0 + wr * 64 + i * 16 + kg * 4 + r;
                if (m < M) {
                    float v = acc[i][j][r] + bn;
                    if (res)  v += res[(size_t)m * N + n];
                    if (relu) v = fmaxf(v, 0.f);
                    if constexpr (sizeof(TC) == 4) C[(size_t)m * N + n] = v;
                    else                           C[(size_t)m * N + n] = (TC)(u16)f2bf(v);
                }
            }
        }
    }
}

// ---------------------------------------------------------------------------
// MFMA flash attention. QK fused layout: row stride 512 (Q at +0, K at +256);
// V separate, stride 256. Otherwise identical to the verified round-5 kernel.
// ---------------------------------------------------------------------------
#define LDA2 40
#define LDP  72
__global__ __launch_bounds__(256) void attn_mfma_kernel(const u16* __restrict__ QKg,
                                                        const u16* __restrict__ Vg,
                                                        u16* __restrict__ Og) {
    __shared__ __align__(16) u16 Ks[64 * LDA2];
    __shared__ __align__(16) u16 Vs[64 * LDA2];
    __shared__ __align__(16) u16 Ps[4][16 * LDP];

    const int qt = blockIdx.x, h = blockIdx.y, b = blockIdx.z;
    const int t  = threadIdx.x;
    const int wq = t >> 6;
    const int lane = t & 63;
    const int l15  = lane & 15;
    const int g    = lane >> 4;
    const int q0   = qt * 64;

    const int srow = t >> 2;
    const int sd   = (t & 3) * 8;

    int qrow = q0 + wq * 16 + l15;
    if (qrow > LQ_ - 1) qrow = LQ_ - 1;
    const bf16x8 qfrag = *(const bf16x8*)(QKg + ((size_t)(b * LQ_) + qrow) * 512 + h * HD_ + g * 8);

    float m_i = -1e30f, l_i = 0.f;
    f32x4 o_acc[2] = {};
    const float scale = 0.17677669529663687f;

    for (int k0 = 0; k0 < 960; k0 += 64) {
        {
            int kr = k0 + srow;
            bf16x8 kv, vv;
            if (kr < LQ_) {
                kv = *(const bf16x8*)(QKg + ((size_t)(b * LQ_) + kr) * 512 + 256 + h * HD_ + sd);
                vv = *(const bf16x8*)(Vg + ((size_t)(b * LQ_) + kr) * D_ + h * HD_ + sd);
            } else {
                #pragma unroll
                for (int j = 0; j < 8; ++j) { kv[j] = 0; vv[j] = 0; }
            }
            *(bf16x8*)&Ks[srow * LDA2 + sd] = kv;
            *(bf16x8*)&Vs[srow * LDA2 + sd] = vv;
        }
        __syncthreads();

        float p[4][4];
        float tmax = -1e30f;
        #pragma unroll
        for (int kt = 0; kt < 4; ++kt) {
            bf16x8 af = *(const bf16x8*)&Ks[(kt * 16 + l15) * LDA2 + g * 8];
            f32x4 c = {0.f, 0.f, 0.f, 0.f};
            c = __builtin_amdgcn_mfma_f32_16x16x32_bf16(af, qfrag, c, 0, 0, 0);
            #pragma unroll
            for (int r = 0; r < 4; ++r) {
                int kglob = k0 + kt * 16 + g * 4 + r;
                float s = (kglob < LQ_) ? c[r] * scale : -1e30f;
                p[kt][r] = s;
                tmax = fmaxf(tmax, s);
            }
        }
        tmax = fmaxf(tmax, __shfl_xor(tmax, 16));
        tmax = fmaxf(tmax, __shfl_xor(tmax, 32));
        float newm = fmaxf(m_i, tmax);
        float corr = __expf(m_i - newm);
        float rs = 0.f;
        #pragma unroll
        for (int kt = 0; kt < 4; ++kt) {
            #pragma unroll
            for (int r = 0; r < 4; ++r) {
                float e = __expf(p[kt][r] - newm);
                p[kt][r] = e;
                rs += e;
            }
            ushort4 pk;
            pk.x = (u16)f2bf(p[kt][0]);
            pk.y = (u16)f2bf(p[kt][1]);
            pk.z = (u16)f2bf(p[kt][2]);
            pk.w = (u16)f2bf(p[kt][3]);
            *(ushort4*)&Ps[wq][l15 * LDP + kt * 16 + g * 4] = pk;
        }
        rs += __shfl_xor(rs, 16);
        rs += __shfl_xor(rs, 32);
        l_i = l_i * corr + rs;
        m_i = newm;

        #pragma unroll
        for (int r = 0; r < 4; ++r) {
            float cq = __shfl(corr, g * 4 + r);
            o_acc[0][r] *= cq;
            o_acc[1][r] *= cq;
        }

        #pragma unroll
        for (int c = 0; c < 2; ++c) {
            bf16x8 pa = *(const bf16x8*)&Ps[wq][l15 * LDP + c * 32 + g * 8];
            #pragma unroll
            for (int nt = 0; nt < 2; ++nt) {
                short vv[8];
                #pragma unroll
                for (int j = 0; j < 8; ++j)
                    vv[j] = (short)Vs[(c * 32 + g * 8 + j) * LDA2 + nt * 16 + l15];
                o_acc[nt] = __builtin_amdgcn_mfma_f32_16x16x32_bf16(pa, *(bf16x8*)vv, o_acc[nt], 0, 0, 0);
            }
        }
        __syncthreads();
    }

    float il = 1.f / l_i;
    #pragma unroll
    for (int r = 0; r < 4; ++r) {
        float ilq = __shfl(il, g * 4 + r);
        int q = q0 + wq * 16 + g * 4 + r;
        if (q < LQ_) {
            u16* dst = Og + ((size_t)(b * LQ_) + q) * D_ + h * HD_ + l15;
            dst[0]  = (u16)f2bf(o_acc[0][r] * ilq);
            dst[16] = (u16)f2bf(o_acc[1][r] * ilq);
        }
    }
}

// ---------------------------------------------------------------------------
// LayerNorm over D=256; optional bf16 second output
// ---------------------------------------------------------------------------
__global__ __launch_bounds__(256) void ln_kernel(const float* __restrict__ X,
                                                 const float* __restrict__ g,
                                                 const float* __restrict__ bb,
                                                 float* __restrict__ Y,
                                                 u16* __restrict__ Yb, int M) {
    int row  = blockIdx.x * 4 + (threadIdx.x >> 6);
    int lane = threadIdx.x & 63;
    if (row >= M) return;
    const float* x = X + (size_t)row * D_;
    float4 v = *(const float4*)(x + lane * 4);
    float s = v.x + v.y + v.z + v.w;
    #pragma unroll
    for (int o = 32; o >= 1; o >>= 1) s += __shfl_xor(s, o);
    float mean = s * (1.f / D_);
    float dx0 = v.x - mean, dx1 = v.y - mean, dx2 = v.z - mean, dx3 = v.w - mean;
    float ss = dx0 * dx0 + dx1 * dx1 + dx2 * dx2 + dx3 * dx3;
    #pragma unroll
    for (int o = 32; o >= 1; o >>= 1) ss += __shfl_xor(ss, o);
    float rstd = rsqrtf(ss * (1.f / D_) + 1e-5f);
    float4 gv = *(const float4*)(g + lane * 4);
    float4 bv = *(const float4*)(bb + lane * 4);
    float4 out;
    out.x = dx0 * rstd * gv.x + bv.x;
    out.y = dx1 * rstd * gv.y + bv.y;
    out.z = dx2 * rstd * gv.z + bv.z;
    out.w = dx3 * rstd * gv.w + bv.w;
    *(float4*)(Y + (size_t)row * D_ + lane * 4) = out;
    if (Yb) {
        ushort4 ob;
        ob.x = (u16)f2bf(out.x); ob.y = (u16)f2bf(out.y);
        ob.z = (u16)f2bf(out.z); ob.w = (u16)f2bf(out.w);
        *(ushort4*)(Yb + (size_t)row * D_ + lane * 4) = ob;
    }
}

// ---------------------------------------------------------------------------
// softmax over 16: logits live in fused (M,384) buffer at col 256 + h*16
// ---------------------------------------------------------------------------
__global__ __launch_bounds__(256) void softmax16v_kernel(const float* __restrict__ X,
                                                         float* __restrict__ Y,
                                                         int rows) {
    int r = blockIdx.x * blockDim.x + threadIdx.x;
    if (r >= rows) return;
    const float* x = X + (size_t)(r >> 3) * 384 + 256 + (r & 7) * 16;
    float m = -1e30f;
    #pragma unroll
    for (int i = 0; i < 16; ++i) m = fmaxf(m, x[i]);
    float e[16], s = 0.f;
    #pragma unroll
    for (int i = 0; i < 16; ++i) { e[i] = expf(x[i] - m); s += e[i]; }
    float inv = 1.f / s;
    float* y = Y + (size_t)r * 16;
    #pragma unroll
    for (int i = 0; i < 16; ++i) y[i] = e[i] * inv;
}

// ---------------------------------------------------------------------------
// multi-scale deformable sampling: thread = (b,q,h, 8-dim slice); bf16 value;
// offsets come from the fused (M,384) buffer (cols 0..255).
// ---------------------------------------------------------------------------
__global__ __launch_bounds__(256) void msdeform2_kernel(const u16* __restrict__ value,
                                                        const float* __restrict__ ref,
                                                        const float* __restrict__ off,
                                                        const float* __restrict__ attw,
                                                        u16* __restrict__ out) {
    const int levH[4] = {128, 64, 32, 16};
    const int levW[4] = {128, 64, 32, 16};
    const int levS[4] = {0, 16384, 20480, 21504};

    int gid = blockIdx.x * 256 + threadIdx.x;     // B*LQ*NH*4 = 460800
    int d8  = gid & 3;
    int bqh = gid >> 2;
    int h   = bqh & (NH_ - 1);
    int bq  = bqh >> 3;
    int b   = bq / LQ_;

    const float* refp = ref  + (size_t)bq * NL_ * 2;
    const float* offp = off  + (size_t)bq * 384 + h * 32;
    const float* awp  = attw + (size_t)bq * 128 + h * 16;
    const u16* vbase  = value + (size_t)b * LIN_ * D_ + h * HD_ + d8 * 8;

    float acc[8] = {};
    #pragma unroll
    for (int l = 0; l < NL_; ++l) {
        float rx = refp[l * 2 + 0], ry = refp[l * 2 + 1];
        const int wl = levW[l], hl = levH[l];
        const u16* vlev = vbase + (size_t)levS[l] * D_;
        #pragma unroll
        for (int p = 0; p < NP_; ++p) {
            float ox = offp[(l * NP_ + p) * 2 + 0];
            float oy = offp[(l * NP_ + p) * 2 + 1];
            float x = rx * wl + ox - 0.5f;
            float y = ry * hl + oy - 0.5f;
            float x0f = floorf(x), y0f = floorf(y);
            float fx = x - x0f, fy = y - y0f;
            int x0 = (int)x0f, y0 = (int)y0f;
            float aw = awp[l * NP_ + p];
            #pragma unroll
            for (int dy = 0; dy < 2; ++dy) {
                int   yi = y0 + dy;
                float wy = dy ? fy : 1.f - fy;
                bool  vy = (yi >= 0) && (yi < hl);
                int   yc = min(max(yi, 0), hl - 1);
                #pragma unroll
                for (int dx = 0; dx < 2; ++dx) {
                    int   xi = x0 + dx;
                    float wx = dx ? fx : 1.f - fx;
                    bool  vx = (xi >= 0) && (xi < wl);
                    int   xc = min(max(xi, 0), wl - 1);
                    float w  = (vx && vy) ? aw * wy * wx : 0.f;
                    bf16x8 v = *(const bf16x8*)(vlev + (size_t)(yc * wl + xc) * D_);
                    #pragma unroll
                    for (int j = 0; j < 8; ++j)
                        acc[j] += w * bf2f((u16)v[j]);
                }
            }
        }
    }
    short o[8];
    #pragma unroll
    for (int j = 0; j < 8; ++j) o[j] = f2bf(acc[j]);
    *(bf16x8*)(out + (size_t)bq * D_ + h * HD_ + d8 * 8) = *(bf16x8*)o;
}

// ---------------------------------------------------------------------------
extern "C" void kernel_launch(void* const* d_in, const int* in_sizes, int n_in,
                              void* d_out, int out_size, void* d_ws, size_t ws_size,
                              hipStream_t stream) {
    const float* queries      = (const float*)d_in[0];
    const float* features     = (const float*)d_in[1];
    const float* refpts       = (const float*)d_in[2];
    const float* q_pos        = (const float*)d_in[3];
    const float* in_proj_w    = (const float*)d_in[4];
    const float* in_proj_b    = (const float*)d_in[5];
    const float* out_proj_w   = (const float*)d_in[6];
    const float* out_proj_b   = (const float*)d_in[7];
    const float* value_proj_w = (const float*)d_in[8];
    const float* value_proj_b = (const float*)d_in[9];
    const float* samp_w       = (const float*)d_in[10];
    const float* samp_b       = (const float*)d_in[11];
    const float* attw_w       = (const float*)d_in[12];
    const float* attw_b       = (const float*)d_in[13];
    const float* msout_w      = (const float*)d_in[14];
    const float* msout_b      = (const float*)d_in[15];
    const float* ffn_w1       = (const float*)d_in[16];
    const float* ffn_b1       = (const float*)d_in[17];
    const float* ffn_w2       = (const float*)d_in[18];
    const float* ffn_b2       = (const float*)d_in[19];
    const float* ln1_g        = (const float*)d_in[20];
    const float* ln1_b        = (const float*)d_in[21];
    const float* ln2_g        = (const float*)d_in[22];
    const float* ln2_b        = (const float*)d_in[23];
    const float* ln3_g        = (const float*)d_in[24];
    const float* ln3_b        = (const float*)d_in[25];

    float* ws = (float*)d_ws;
    const size_t NQ = (size_t)B_ * LQ_ * D_;          // 3,686,400
    // f32 scratch
    float* bufB = ws;                                  // (M,384) samp+attw logits
    float* bufC = ws + 3 * NQ / 2;                     // (M,256) pre-LN / post-FFN2
    float* bufF = bufC + NQ;                           // x (post-LN1)
    float* bufD = bufF + NQ;                           // attw softmax; later LN2 f32
    // bf16 scratch
    u16* U    = (u16*)(bufD + NQ);
    u16* qkb  = U;                                     // bf16(queries+q_pos)
    u16* qb   = U + NQ;                                // bf16(queries)
    u16* q2b  = U + 2 * NQ;                            // bf16(x+q_pos)
    u16* QKb  = U + 3 * NQ;                            // (M,512) fused Q|K
    u16* Vb   = U + 5 * NQ;
    u16* Ob   = U + 6 * NQ;
    u16* MSb  = U + 7 * NQ;
    u16* LN2b = U + 8 * NQ;
    u16* VALb = U + 9 * NQ;                            // (B, LIN, 256)
    u16* H1b  = VALb + (size_t)B_ * LIN_ * D_;         // (M, 2048)
    u16* Wb   = H1b + (size_t)B_ * LQ_ * DFFN_;        // all weights bf16
    float* Bb = (float*)(Wb + WTOTAL);                 // concat biases f32

    const int M = B_ * LQ_;           // 14400 (MT=900)

    // 0. weight + bias prep
    wprep_kernel<<<752, 256, 0, stream>>>(in_proj_w, out_proj_w, value_proj_w, samp_w,
                                          attw_w, msout_w, ffn_w1, ffn_w2, Wb);
    bprep_kernel<<<17, 256, 0, stream>>>(in_proj_b, out_proj_b, value_proj_b, samp_b,
                                         attw_b, msout_b, ffn_b1, ffn_b2, Bb);

    // 1. qkb = bf16(queries + q_pos); qb = bf16(queries)
    add_bf16_kernel<<<3600, 256, 0, stream>>>(queries, q_pos, qkb, qb, NQ / 4);

    // 2. fused Q|K (N=512, NS=16, CH=4 -> 3600 jobs) and V (N=256, NS=8 -> 1800 jobs)
    wsgemm_kernel<u16, u16><<<900, 256, 0, stream>>>(qkb, Wb + WOFF_INPROJ, Bb + BOFF_INPROJ, nullptr, QKb, 900, 16, 4, 512, 0);
    wsgemm_kernel<u16, u16><<<450, 256, 0, stream>>>(qb, Wb + WOFF_INPROJ + 131072, Bb + BOFF_INPROJ + 512, nullptr, Vb, 900, 8, 4, 256, 0);

    // 3. attention -> Ob
    attn_mfma_kernel<<<dim3(15, NH_, B_), 256, 0, stream>>>(QKb, Vb, Ob);

    // 4. out-proj + residual(queries) -> bufC; 5. LN1 -> bufF
    wsgemm_kernel<u16, float><<<450, 256, 0, stream>>>(Ob, Wb + WOFF_OUTPROJ, Bb + BOFF_OUTPROJ, queries, bufC, 900, 8, 4, 256, 0);
    ln_kernel<<<3600, 256, 0, stream>>>(bufC, ln1_g, ln1_b, bufF, nullptr, M);

    // 6. q2b = bf16(x + q_pos)
    add_bf16_kernel<<<3600, 256, 0, stream>>>(bufF, q_pos, q2b, nullptr, NQ / 4);

    // 7. value projection (f32 A): MT=21760, NS=8, CH=32 -> 5440 jobs
    wsgemm_kernel<float, u16><<<1360, 256, 0, stream>>>(features, Wb + WOFF_VALPROJ, Bb + BOFF_VALPROJ, nullptr, VALb, 21760, 8, 32, 256, 0);

    // 8. fused samp+attw (N=384, NS=12 -> 2700 jobs) -> bufB
    wsgemm_kernel<u16, float><<<675, 256, 0, stream>>>(q2b, Wb + WOFF_SAMP, Bb + BOFF_SAMPATT, nullptr, bufB, 900, 12, 4, 384, 0);

    // 9. softmax over 16 -> bufD
    softmax16v_kernel<<<450, 256, 0, stream>>>(bufB, bufD, B_ * LQ_ * NH_);

    // 10. deformable sampling -> MSb
    msdeform2_kernel<<<1800, 256, 0, stream>>>(VALb, refpts, bufB, bufD, MSb);

    // 11. msout + residual(bufF) -> bufC; 12. LN2 -> bufD(f32) + LN2b(bf16)
    wsgemm_kernel<u16, float><<<450, 256, 0, stream>>>(MSb, Wb + WOFF_MSOUT, Bb + BOFF_MSOUT, bufF, bufC, 900, 8, 4, 256, 0);
    ln_kernel<<<3600, 256, 0, stream>>>(bufC, ln2_g, ln2_b, bufD, LN2b, M);

    // 13. FFN up + ReLU (N=2048, NS=64 -> 14400 jobs) -> H1b
    wsgemm_kernel<u16, u16><<<3600, 256, 0, stream>>>(LN2b, Wb + WOFF_FFN1, Bb + BOFF_FFN1, nullptr, H1b, 900, 64, 4, 2048, 1);

    // 14. FFN down (K=2048, gemm2) + residual(bufD) -> bufC; 15. LN3 -> d_out
    gemm2_kernel<u16, float><<<dim3(2, 113), 256, 0, stream>>>(H1b, Wb + WOFF_FFN2, ffn_b2, bufD, bufC, M, 256, 2048, 0);
    ln_kernel<<<3600, 256, 0, stream>>>(bufC, ln3_g, ln3_b, (float*)d_out, nullptr, M);
}

// Round 8
// 1094.684 us; speedup vs baseline: 1.2812x; 1.2812x over previous
//
#include <hip/hip_runtime.h>
#include <hip/hip_bf16.h>
#include <math.h>

#define B_    16
#define LQ_   900
#define D_    256
#define NH_   8
#define HD_   32
#define NL_   4
#define NP_   4
#define DFFN_ 2048
#define LIN_  21760

typedef unsigned short u16;
typedef __attribute__((ext_vector_type(8))) short bf16x8;
typedef __attribute__((ext_vector_type(4))) float f32x4;

__device__ __forceinline__ short f2bf(float f) {
    unsigned u = __float_as_uint(f);
    u += 0x7fffu + ((u >> 16) & 1u);   // RNE
    return (short)(u >> 16);
}
__device__ __forceinline__ float bf2f(u16 u) {
    return __uint_as_float(((unsigned)u) << 16);
}

// ---------------------------------------------------------------------------
// weight prep: fp32 weights -> bf16 Wb (samp & attw ADJACENT for N=384 fusion)
// ---------------------------------------------------------------------------
#define WOFF_INPROJ  0
#define WOFF_OUTPROJ 196608
#define WOFF_VALPROJ 262144
#define WOFF_SAMP    327680
#define WOFF_ATTW    393216
#define WOFF_MSOUT   425984
#define WOFF_FFN1    491520
#define WOFF_FFN2    1015808
#define WTOTAL       1540096

__global__ __launch_bounds__(256) void wprep_kernel(const float* __restrict__ s0,
                                                    const float* __restrict__ s1,
                                                    const float* __restrict__ s2,
                                                    const float* __restrict__ s3,
                                                    const float* __restrict__ s4,
                                                    const float* __restrict__ s5,
                                                    const float* __restrict__ s6,
                                                    const float* __restrict__ s7,
                                                    u16* __restrict__ Wb) {
    int i8 = (blockIdx.x * 256 + threadIdx.x) * 8;
    if (i8 >= WTOTAL) return;
    const float* src; int rel;
    if      (i8 < WOFF_OUTPROJ) { src = s0; rel = i8; }
    else if (i8 < WOFF_VALPROJ) { src = s1; rel = i8 - WOFF_OUTPROJ; }
    else if (i8 < WOFF_SAMP)    { src = s2; rel = i8 - WOFF_VALPROJ; }
    else if (i8 < WOFF_ATTW)    { src = s3; rel = i8 - WOFF_SAMP; }
    else if (i8 < WOFF_MSOUT)   { src = s4; rel = i8 - WOFF_ATTW; }
    else if (i8 < WOFF_FFN1)    { src = s5; rel = i8 - WOFF_MSOUT; }
    else if (i8 < WOFF_FFN2)    { src = s6; rel = i8 - WOFF_FFN1; }
    else                        { src = s7; rel = i8 - WOFF_FFN2; }
    float4 v0 = *(const float4*)(src + rel);
    float4 v1 = *(const float4*)(src + rel + 4);
    short o[8];
    o[0] = f2bf(v0.x); o[1] = f2bf(v0.y); o[2] = f2bf(v0.z); o[3] = f2bf(v0.w);
    o[4] = f2bf(v1.x); o[5] = f2bf(v1.y); o[6] = f2bf(v1.z); o[7] = f2bf(v1.w);
    *(bf16x8*)(Wb + i8) = *(bf16x8*)o;
}

// bias concat (f32)
#define BOFF_INPROJ  0
#define BOFF_OUTPROJ 768
#define BOFF_VALPROJ 1024
#define BOFF_SAMPATT 1280
#define BOFF_MSOUT   1664
#define BOFF_FFN1    1920
#define BOFF_FFN2    3968
#define BTOTAL       4224

__global__ __launch_bounds__(256) void bprep_kernel(const float* __restrict__ b0,
                                                    const float* __restrict__ b1,
                                                    const float* __restrict__ b2,
                                                    const float* __restrict__ b3,
                                                    const float* __restrict__ b4,
                                                    const float* __restrict__ b5,
                                                    const float* __restrict__ b6,
                                                    const float* __restrict__ b7,
                                                    float* __restrict__ Bb) {
    int i = blockIdx.x * 256 + threadIdx.x;
    if (i >= BTOTAL) return;
    const float* s; int rel;
    if      (i < BOFF_OUTPROJ) { s = b0; rel = i; }
    else if (i < BOFF_VALPROJ) { s = b1; rel = i - BOFF_OUTPROJ; }
    else if (i < BOFF_SAMPATT) { s = b2; rel = i - BOFF_VALPROJ; }
    else if (i < 1536)         { s = b3; rel = i - BOFF_SAMPATT; }
    else if (i < BOFF_MSOUT)   { s = b4; rel = i - 1536; }
    else if (i < BOFF_FFN1)    { s = b5; rel = i - BOFF_MSOUT; }
    else if (i < BOFF_FFN2)    { s = b6; rel = i - BOFF_FFN1; }
    else                       { s = b7; rel = i - BOFF_FFN2; }
    Bb[i] = s[rel];
}

// ---------------------------------------------------------------------------
// fused add -> bf16 (and optional bf16 copy of input a)
// ---------------------------------------------------------------------------
__global__ __launch_bounds__(256) void add_bf16_kernel(const float* __restrict__ a,
                                                       const float* __restrict__ b,
                                                       u16* __restrict__ osum,
                                                       u16* __restrict__ oa,
                                                       size_t n4) {
    size_t i = (size_t)blockIdx.x * blockDim.x + threadIdx.x;
    if (i >= n4) return;
    float4 x = ((const float4*)a)[i];
    float4 y = ((const float4*)b)[i];
    ushort4 s;
    s.x = (u16)f2bf(x.x + y.x); s.y = (u16)f2bf(x.y + y.y);
    s.z = (u16)f2bf(x.z + y.z); s.w = (u16)f2bf(x.w + y.w);
    ((ushort4*)osum)[i] = s;
    if (oa) {
        ushort4 q;
        q.x = (u16)f2bf(x.x); q.y = (u16)f2bf(x.y);
        q.z = (u16)f2bf(x.z); q.w = (u16)f2bf(x.w);
        ((ushort4*)oa)[i] = q;
    }
}

// ---------------------------------------------------------------------------
// gemm3: pipelined bf16 MFMA GEMM with 2-DEEP register prefetch.
// C[M,N] = A[M,K] @ W[N,K]^T + bias (+res f32)(+relu). W pre-converted bf16.
// 128x128 tile, BK=32, 256 thr (4 waves 2x2), double-buffered LDS, one
// barrier per K-step. Named register sets (0/1) with static parity unroll
// (rule #20: no runtime indexing). In-flight: 2 K-steps of loads per wave.
// ---------------------------------------------------------------------------
#define LDK 40
template <typename TA, typename TC>
__global__ __launch_bounds__(256) void gemm3_kernel(const TA* __restrict__ A,
                                                    const u16* __restrict__ W,
                                                    const float* __restrict__ bias,
                                                    const float* __restrict__ res,
                                                    TC* __restrict__ C,
                                                    int M, int N, int K, int relu) {
    __shared__ __align__(16) u16 As[2][128 * LDK];
    __shared__ __align__(16) u16 Bs[2][128 * LDK];

    const int n0 = blockIdx.x * 128;
    const int m0 = blockIdx.y * 128;
    const int t  = threadIdx.x;
    const int srow = t >> 1;
    const int scol = (t & 1) << 4;
    const int lane = t & 63;
    const int lr   = lane & 15;
    const int kg   = lane >> 4;
    const int wid  = t >> 6;
    const int wr   = wid >> 1;
    const int wc   = wid & 1;

    f32x4 acc[4][4] = {};

    const int  nk  = K >> 5;
    const int  gm  = m0 + srow;
    const bool mok = (gm < M);

    const float* af32 = (const float*)A + (size_t)(mok ? gm : 0) * K + scol;
    const u16*   ab16 = (const u16*)A + (size_t)(mok ? gm : 0) * K + scol;
    const u16*   wp   = W + (size_t)(n0 + srow) * K + scol;

    float4 af0[4], af1[4];
    bf16x8 ab0[2], ab1[2];
    bf16x8 wf0[2], wf1[2];
    if (!mok) {
        #pragma unroll
        for (int q = 0; q < 4; ++q) af0[q] = af1[q] = make_float4(0.f, 0.f, 0.f, 0.f);
        #pragma unroll
        for (int q = 0; q < 8; ++q) { ab0[0][q] = 0; ab0[1][q] = 0; ab1[0][q] = 0; ab1[1][q] = 0; }
    }

#define GLOAD_A_F(afX, kt_) do { if (mok) { \
        _Pragma("unroll") for (int q = 0; q < 4; ++q) afX[q] = *(const float4*)(af32 + ((kt_) << 5) + q * 4); } } while (0)
#define GLOAD_A_B(abX, kt_) do { if (mok) { \
        abX[0] = *(const bf16x8*)(ab16 + ((kt_) << 5)); \
        abX[1] = *(const bf16x8*)(ab16 + ((kt_) << 5) + 8); } } while (0)
#define GLOAD_W(wfX, kt_) do { \
        wfX[0] = *(const bf16x8*)(wp + ((kt_) << 5)); \
        wfX[1] = *(const bf16x8*)(wp + ((kt_) << 5) + 8); } while (0)

#define DSWRITE(bufI, afX, abX, wfX) do { \
        if constexpr (sizeof(TA) == 4) { \
            short tmp[16]; \
            _Pragma("unroll") for (int q = 0; q < 4; ++q) { \
                tmp[q * 4 + 0] = f2bf(afX[q].x); tmp[q * 4 + 1] = f2bf(afX[q].y); \
                tmp[q * 4 + 2] = f2bf(afX[q].z); tmp[q * 4 + 3] = f2bf(afX[q].w); } \
            *(bf16x8*)&As[bufI][srow * LDK + scol]     = *(bf16x8*)tmp; \
            *(bf16x8*)&As[bufI][srow * LDK + scol + 8] = *(bf16x8*)(tmp + 8); \
        } else { \
            *(bf16x8*)&As[bufI][srow * LDK + scol]     = abX[0]; \
            *(bf16x8*)&As[bufI][srow * LDK + scol + 8] = abX[1]; } \
        *(bf16x8*)&Bs[bufI][srow * LDK + scol]     = wfX[0]; \
        *(bf16x8*)&Bs[bufI][srow * LDK + scol + 8] = wfX[1]; } while (0)

    auto domfma = [&](const u16* bufA, const u16* bufB) {
        const u16* pA = bufA + (wr * 64 + lr) * LDK + kg * 8;
        const u16* pB = bufB + (wc * 64 + lr) * LDK + kg * 8;
        bf16x8 a[4], b[4];
        #pragma unroll
        for (int i = 0; i < 4; ++i) a[i] = *(const bf16x8*)(pA + i * 16 * LDK);
        #pragma unroll
        for (int j = 0; j < 4; ++j) b[j] = *(const bf16x8*)(pB + j * 16 * LDK);
        #pragma unroll
        for (int i = 0; i < 4; ++i)
            #pragma unroll
            for (int j = 0; j < 4; ++j)
                acc[i][j] = __builtin_amdgcn_mfma_f32_16x16x32_bf16(a[i], b[j], acc[i][j], 0, 0, 0);
    };

    // prologue: fill both register sets (k-steps 0 and 1; nk >= 2 always here)
    if constexpr (sizeof(TA) == 4) { GLOAD_A_F(af0, 0); GLOAD_A_F(af1, 1); }
    else                           { GLOAD_A_B(ab0, 0); GLOAD_A_B(ab1, 1); }
    GLOAD_W(wf0, 0); GLOAD_W(wf1, 1);

    int kt = 0;
    while (true) {
        // even step: set 0 -> buf 0
        DSWRITE(0, af0, ab0, wf0);
        if (kt + 2 < nk) {
            if constexpr (sizeof(TA) == 4) GLOAD_A_F(af0, kt + 2); else GLOAD_A_B(ab0, kt + 2);
            GLOAD_W(wf0, kt + 2);
        }
        __syncthreads();
        domfma(&As[0][0], &Bs[0][0]);
        if (++kt >= nk) break;
        // odd step: set 1 -> buf 1
        DSWRITE(1, af1, ab1, wf1);
        if (kt + 2 < nk) {
            if constexpr (sizeof(TA) == 4) GLOAD_A_F(af1, kt + 2); else GLOAD_A_B(ab1, kt + 2);
            GLOAD_W(wf1, kt + 2);
        }
        __syncthreads();
        domfma(&As[1][0], &Bs[1][0]);
        if (++kt >= nk) break;
    }
#undef GLOAD_A_F
#undef GLOAD_A_B
#undef GLOAD_W
#undef DSWRITE

    // epilogue: D row = kg*4 + r, col = lr (m89-verified)
    #pragma unroll
    for (int i = 0; i < 4; ++i) {
        #pragma unroll
        for (int j = 0; j < 4; ++j) {
            const int n = n0 + wc * 64 + j * 16 + lr;
            const float bn = bias[n];
            #pragma unroll
            for (int r = 0; r < 4; ++r) {
                const int m = m0 + wr * 64 + i * 16 + kg * 4 + r;
                if (m < M) {
                    float v = acc[i][j][r] + bn;
                    if (res)  v += res[(size_t)m * N + n];
                    if (relu) v = fmaxf(v, 0.f);
                    if constexpr (sizeof(TC) == 4) C[(size_t)m * N + n] = v;
                    else                           C[(size_t)m * N + n] = (TC)(u16)f2bf(v);
                }
            }
        }
    }
}

// ---------------------------------------------------------------------------
// MFMA flash attention. QK fused layout: row stride 512 (Q at +0, K at +256);
// V separate, stride 256. (verified round 7)
// ---------------------------------------------------------------------------
#define LDA2 40
#define LDP  72
__global__ __launch_bounds__(256) void attn_mfma_kernel(const u16* __restrict__ QKg,
                                                        const u16* __restrict__ Vg,
                                                        u16* __restrict__ Og) {
    __shared__ __align__(16) u16 Ks[64 * LDA2];
    __shared__ __align__(16) u16 Vs[64 * LDA2];
    __shared__ __align__(16) u16 Ps[4][16 * LDP];

    const int qt = blockIdx.x, h = blockIdx.y, b = blockIdx.z;
    const int t  = threadIdx.x;
    const int wq = t >> 6;
    const int lane = t & 63;
    const int l15  = lane & 15;
    const int g    = lane >> 4;
    const int q0   = qt * 64;

    const int srow = t >> 2;
    const int sd   = (t & 3) * 8;

    int qrow = q0 + wq * 16 + l15;
    if (qrow > LQ_ - 1) qrow = LQ_ - 1;
    const bf16x8 qfrag = *(const bf16x8*)(QKg + ((size_t)(b * LQ_) + qrow) * 512 + h * HD_ + g * 8);

    float m_i = -1e30f, l_i = 0.f;
    f32x4 o_acc[2] = {};
    const float scale = 0.17677669529663687f;

    for (int k0 = 0; k0 < 960; k0 += 64) {
        {
            int kr = k0 + srow;
            bf16x8 kv, vv;
            if (kr < LQ_) {
                kv = *(const bf16x8*)(QKg + ((size_t)(b * LQ_) + kr) * 512 + 256 + h * HD_ + sd);
                vv = *(const bf16x8*)(Vg + ((size_t)(b * LQ_) + kr) * D_ + h * HD_ + sd);
            } else {
                #pragma unroll
                for (int j = 0; j < 8; ++j) { kv[j] = 0; vv[j] = 0; }
            }
            *(bf16x8*)&Ks[srow * LDA2 + sd] = kv;
            *(bf16x8*)&Vs[srow * LDA2 + sd] = vv;
        }
        __syncthreads();

        float p[4][4];
        float tmax = -1e30f;
        #pragma unroll
        for (int kt = 0; kt < 4; ++kt) {
            bf16x8 af = *(const bf16x8*)&Ks[(kt * 16 + l15) * LDA2 + g * 8];
            f32x4 c = {0.f, 0.f, 0.f, 0.f};
            c = __builtin_amdgcn_mfma_f32_16x16x32_bf16(af, qfrag, c, 0, 0, 0);
            #pragma unroll
            for (int r = 0; r < 4; ++r) {
                int kglob = k0 + kt * 16 + g * 4 + r;
                float s = (kglob < LQ_) ? c[r] * scale : -1e30f;
                p[kt][r] = s;
                tmax = fmaxf(tmax, s);
            }
        }
        tmax = fmaxf(tmax, __shfl_xor(tmax, 16));
        tmax = fmaxf(tmax, __shfl_xor(tmax, 32));
        float newm = fmaxf(m_i, tmax);
        float corr = __expf(m_i - newm);
        float rs = 0.f;
        #pragma unroll
        for (int kt = 0; kt < 4; ++kt) {
            #pragma unroll
            for (int r = 0; r < 4; ++r) {
                float e = __expf(p[kt][r] - newm);
                p[kt][r] = e;
                rs += e;
            }
            ushort4 pk;
            pk.x = (u16)f2bf(p[kt][0]);
            pk.y = (u16)f2bf(p[kt][1]);
            pk.z = (u16)f2bf(p[kt][2]);
            pk.w = (u16)f2bf(p[kt][3]);
            *(ushort4*)&Ps[wq][l15 * LDP + kt * 16 + g * 4] = pk;
        }
        rs += __shfl_xor(rs, 16);
        rs += __shfl_xor(rs, 32);
        l_i = l_i * corr + rs;
        m_i = newm;

        #pragma unroll
        for (int r = 0; r < 4; ++r) {
            float cq = __shfl(corr, g * 4 + r);
            o_acc[0][r] *= cq;
            o_acc[1][r] *= cq;
        }

        #pragma unroll
        for (int c = 0; c < 2; ++c) {
            bf16x8 pa = *(const bf16x8*)&Ps[wq][l15 * LDP + c * 32 + g * 8];
            #pragma unroll
            for (int nt = 0; nt < 2; ++nt) {
                short vv[8];
                #pragma unroll
                for (int j = 0; j < 8; ++j)
                    vv[j] = (short)Vs[(c * 32 + g * 8 + j) * LDA2 + nt * 16 + l15];
                o_acc[nt] = __builtin_amdgcn_mfma_f32_16x16x32_bf16(pa, *(bf16x8*)vv, o_acc[nt], 0, 0, 0);
            }
        }
        __syncthreads();
    }

    float il = 1.f / l_i;
    #pragma unroll
    for (int r = 0; r < 4; ++r) {
        float ilq = __shfl(il, g * 4 + r);
        int q = q0 + wq * 16 + g * 4 + r;
        if (q < LQ_) {
            u16* dst = Og + ((size_t)(b * LQ_) + q) * D_ + h * HD_ + l15;
            dst[0]  = (u16)f2bf(o_acc[0][r] * ilq);
            dst[16] = (u16)f2bf(o_acc[1][r] * ilq);
        }
    }
}

// ---------------------------------------------------------------------------
// LayerNorm over D=256; optional bf16 second output
// ---------------------------------------------------------------------------
__global__ __launch_bounds__(256) void ln_kernel(const float* __restrict__ X,
                                                 const float* __restrict__ g,
                                                 const float* __restrict__ bb,
                                                 float* __restrict__ Y,
                                                 u16* __restrict__ Yb, int M) {
    int row  = blockIdx.x * 4 + (threadIdx.x >> 6);
    int lane = threadIdx.x & 63;
    if (row >= M) return;
    const float* x = X + (size_t)row * D_;
    float4 v = *(const float4*)(x + lane * 4);
    float s = v.x + v.y + v.z + v.w;
    #pragma unroll
    for (int o = 32; o >= 1; o >>= 1) s += __shfl_xor(s, o);
    float mean = s * (1.f / D_);
    float dx0 = v.x - mean, dx1 = v.y - mean, dx2 = v.z - mean, dx3 = v.w - mean;
    float ss = dx0 * dx0 + dx1 * dx1 + dx2 * dx2 + dx3 * dx3;
    #pragma unroll
    for (int o = 32; o >= 1; o >>= 1) ss += __shfl_xor(ss, o);
    float rstd = rsqrtf(ss * (1.f / D_) + 1e-5f);
    float4 gv = *(const float4*)(g + lane * 4);
    float4 bv = *(const float4*)(bb + lane * 4);
    float4 out;
    out.x = dx0 * rstd * gv.x + bv.x;
    out.y = dx1 * rstd * gv.y + bv.y;
    out.z = dx2 * rstd * gv.z + bv.z;
    out.w = dx3 * rstd * gv.w + bv.w;
    *(float4*)(Y + (size_t)row * D_ + lane * 4) = out;
    if (Yb) {
        ushort4 ob;
        ob.x = (u16)f2bf(out.x); ob.y = (u16)f2bf(out.y);
        ob.z = (u16)f2bf(out.z); ob.w = (u16)f2bf(out.w);
        *(ushort4*)(Yb + (size_t)row * D_ + lane * 4) = ob;
    }
}

// ---------------------------------------------------------------------------
// softmax over 16: logits in fused (M,384) buffer at col 256 + h*16
// ---------------------------------------------------------------------------
__global__ __launch_bounds__(256) void softmax16v_kernel(const float* __restrict__ X,
                                                         float* __restrict__ Y,
                                                         int rows) {
    int r = blockIdx.x * blockDim.x + threadIdx.x;
    if (r >= rows) return;
    const float* x = X + (size_t)(r >> 3) * 384 + 256 + (r & 7) * 16;
    float m = -1e30f;
    #pragma unroll
    for (int i = 0; i < 16; ++i) m = fmaxf(m, x[i]);
    float e[16], s = 0.f;
    #pragma unroll
    for (int i = 0; i < 16; ++i) { e[i] = expf(x[i] - m); s += e[i]; }
    float inv = 1.f / s;
    float* y = Y + (size_t)r * 16;
    #pragma unroll
    for (int i = 0; i < 16; ++i) y[i] = e[i] * inv;
}

// ---------------------------------------------------------------------------
// multi-scale deformable sampling: thread = (b,q,h, 8-dim slice); bf16 value;
// offsets from the fused (M,384) buffer (cols 0..255). (verified round 7)
// ---------------------------------------------------------------------------
__global__ __launch_bounds__(256) void msdeform2_kernel(const u16* __restrict__ value,
                                                        const float* __restrict__ ref,
                                                        const float* __restrict__ off,
                                                        const float* __restrict__ attw,
                                                        u16* __restrict__ out) {
    const int levH[4] = {128, 64, 32, 16};
    const int levW[4] = {128, 64, 32, 16};
    const int levS[4] = {0, 16384, 20480, 21504};

    int gid = blockIdx.x * 256 + threadIdx.x;     // B*LQ*NH*4 = 460800
    int d8  = gid & 3;
    int bqh = gid >> 2;
    int h   = bqh & (NH_ - 1);
    int bq  = bqh >> 3;
    int b   = bq / LQ_;

    const float* refp = ref  + (size_t)bq * NL_ * 2;
    const float* offp = off  + (size_t)bq * 384 + h * 32;
    const float* awp  = attw + (size_t)bq * 128 + h * 16;
    const u16* vbase  = value + (size_t)b * LIN_ * D_ + h * HD_ + d8 * 8;

    float acc[8] = {};
    #pragma unroll
    for (int l = 0; l < NL_; ++l) {
        float rx = refp[l * 2 + 0], ry = refp[l * 2 + 1];
        const int wl = levW[l], hl = levH[l];
        const u16* vlev = vbase + (size_t)levS[l] * D_;
        #pragma unroll
        for (int p = 0; p < NP_; ++p) {
            float ox = offp[(l * NP_ + p) * 2 + 0];
            float oy = offp[(l * NP_ + p) * 2 + 1];
            float x = rx * wl + ox - 0.5f;
            float y = ry * hl + oy - 0.5f;
            float x0f = floorf(x), y0f = floorf(y);
            float fx = x - x0f, fy = y - y0f;
            int x0 = (int)x0f, y0 = (int)y0f;
            float aw = awp[l * NP_ + p];
            #pragma unroll
            for (int dy = 0; dy < 2; ++dy) {
                int   yi = y0 + dy;
                float wy = dy ? fy : 1.f - fy;
                bool  vy = (yi >= 0) && (yi < hl);
                int   yc = min(max(yi, 0), hl - 1);
                #pragma unroll
                for (int dx = 0; dx < 2; ++dx) {
                    int   xi = x0 + dx;
                    float wx = dx ? fx : 1.f - fx;
                    bool  vx = (xi >= 0) && (xi < wl);
                    int   xc = min(max(xi, 0), wl - 1);
                    float w  = (vx && vy) ? aw * wy * wx : 0.f;
                    bf16x8 v = *(const bf16x8*)(vlev + (size_t)(yc * wl + xc) * D_);
                    #pragma unroll
                    for (int j = 0; j < 8; ++j)
                        acc[j] += w * bf2f((u16)v[j]);
                }
            }
        }
    }
    short o[8];
    #pragma unroll
    for (int j = 0; j < 8; ++j) o[j] = f2bf(acc[j]);
    *(bf16x8*)(out + (size_t)bq * D_ + h * HD_ + d8 * 8) = *(bf16x8*)o;
}

// ---------------------------------------------------------------------------
extern "C" void kernel_launch(void* const* d_in, const int* in_sizes, int n_in,
                              void* d_out, int out_size, void* d_ws, size_t ws_size,
                              hipStream_t stream) {
    const float* queries      = (const float*)d_in[0];
    const float* features     = (const float*)d_in[1];
    const float* refpts       = (const float*)d_in[2];
    const float* q_pos        = (const float*)d_in[3];
    const float* in_proj_w    = (const float*)d_in[4];
    const float* in_proj_b    = (const float*)d_in[5];
    const float* out_proj_w   = (const float*)d_in[6];
    const float* out_proj_b   = (const float*)d_in[7];
    const float* value_proj_w = (const float*)d_in[8];
    const float* value_proj_b = (const float*)d_in[9];
    const float* samp_w       = (const float*)d_in[10];
    const float* samp_b       = (const float*)d_in[11];
    const float* attw_w       = (const float*)d_in[12];
    const float* attw_b       = (const float*)d_in[13];
    const float* msout_w      = (const float*)d_in[14];
    const float* msout_b      = (const float*)d_in[15];
    const float* ffn_w1       = (const float*)d_in[16];
    const float* ffn_b1       = (const float*)d_in[17];
    const float* ffn_w2       = (const float*)d_in[18];
    const float* ffn_b2       = (const float*)d_in[19];
    const float* ln1_g        = (const float*)d_in[20];
    const float* ln1_b        = (const float*)d_in[21];
    const float* ln2_g        = (const float*)d_in[22];
    const float* ln2_b        = (const float*)d_in[23];
    const float* ln3_g        = (const float*)d_in[24];
    const float* ln3_b        = (const float*)d_in[25];

    float* ws = (float*)d_ws;
    const size_t NQ = (size_t)B_ * LQ_ * D_;          // 3,686,400
    // f32 scratch
    float* bufB = ws;                                  // (M,384) samp+attw logits
    float* bufC = ws + 3 * NQ / 2;                     // (M,256) pre-LN / post-FFN2
    float* bufF = bufC + NQ;                           // x (post-LN1)
    float* bufD = bufF + NQ;                           // attw softmax; later LN2 f32
    // bf16 scratch
    u16* U    = (u16*)(bufD + NQ);
    u16* qkb  = U;                                     // bf16(queries+q_pos)
    u16* qb   = U + NQ;                                // bf16(queries)
    u16* q2b  = U + 2 * NQ;                            // bf16(x+q_pos)
    u16* QKb  = U + 3 * NQ;                            // (M,512) fused Q|K
    u16* Vb   = U + 5 * NQ;
    u16* Ob   = U + 6 * NQ;
    u16* MSb  = U + 7 * NQ;
    u16* LN2b = U + 8 * NQ;
    u16* VALb = U + 9 * NQ;                            // (B, LIN, 256)
    u16* H1b  = VALb + (size_t)B_ * LIN_ * D_;         // (M, 2048)
    u16* Wb   = H1b + (size_t)B_ * LQ_ * DFFN_;        // all weights bf16
    float* Bb = (float*)(Wb + WTOTAL);                 // concat biases f32

    const int M = B_ * LQ_;           // 14400
    const int GY = 113;               // ceil(14400/128)

    // 0. weight + bias prep
    wprep_kernel<<<752, 256, 0, stream>>>(in_proj_w, out_proj_w, value_proj_w, samp_w,
                                          attw_w, msout_w, ffn_w1, ffn_w2, Wb);
    bprep_kernel<<<17, 256, 0, stream>>>(in_proj_b, out_proj_b, value_proj_b, samp_b,
                                         attw_b, msout_b, ffn_b1, ffn_b2, Bb);

    // 1. qkb = bf16(queries + q_pos); qb = bf16(queries)
    add_bf16_kernel<<<3600, 256, 0, stream>>>(queries, q_pos, qkb, qb, NQ / 4);

    // 2. fused Q|K (N=512) and V (N=256)
    gemm3_kernel<u16, u16><<<dim3(4, GY), 256, 0, stream>>>(qkb, Wb + WOFF_INPROJ, Bb + BOFF_INPROJ, nullptr, QKb, M, 512, 256, 0);
    gemm3_kernel<u16, u16><<<dim3(2, GY), 256, 0, stream>>>(qb, Wb + WOFF_INPROJ + 131072, Bb + BOFF_INPROJ + 512, nullptr, Vb, M, 256, 256, 0);

    // 3. attention -> Ob
    attn_mfma_kernel<<<dim3(15, NH_, B_), 256, 0, stream>>>(QKb, Vb, Ob);

    // 4. out-proj + residual(queries) -> bufC; 5. LN1 -> bufF
    gemm3_kernel<u16, float><<<dim3(2, GY), 256, 0, stream>>>(Ob, Wb + WOFF_OUTPROJ, Bb + BOFF_OUTPROJ, queries, bufC, M, 256, 256, 0);
    ln_kernel<<<3600, 256, 0, stream>>>(bufC, ln1_g, ln1_b, bufF, nullptr, M);

    // 6. q2b = bf16(x + q_pos)
    add_bf16_kernel<<<3600, 256, 0, stream>>>(bufF, q_pos, q2b, nullptr, NQ / 4);

    // 7. value projection (f32 A, 2-deep pipelined conversion) -> VALb
    gemm3_kernel<float, u16><<<dim3(2, 2720), 256, 0, stream>>>(features, Wb + WOFF_VALPROJ, Bb + BOFF_VALPROJ, nullptr, VALb, B_ * LIN_, 256, 256, 0);

    // 8. fused samp+attw (N=384) -> bufB
    gemm3_kernel<u16, float><<<dim3(3, GY), 256, 0, stream>>>(q2b, Wb + WOFF_SAMP, Bb + BOFF_SAMPATT, nullptr, bufB, M, 384, 256, 0);

    // 9. softmax over 16 -> bufD
    softmax16v_kernel<<<450, 256, 0, stream>>>(bufB, bufD, B_ * LQ_ * NH_);

    // 10. deformable sampling -> MSb
    msdeform2_kernel<<<1800, 256, 0, stream>>>(VALb, refpts, bufB, bufD, MSb);

    // 11. msout + residual(bufF) -> bufC; 12. LN2 -> bufD(f32) + LN2b(bf16)
    gemm3_kernel<u16, float><<<dim3(2, GY), 256, 0, stream>>>(MSb, Wb + WOFF_MSOUT, Bb + BOFF_MSOUT, bufF, bufC, M, 256, 256, 0);
    ln_kernel<<<3600, 256, 0, stream>>>(bufC, ln2_g, ln2_b, bufD, LN2b, M);

    // 13. FFN up + ReLU (N=2048) -> H1b
    gemm3_kernel<u16, u16><<<dim3(16, GY), 256, 0, stream>>>(LN2b, Wb + WOFF_FFN1, Bb + BOFF_FFN1, nullptr, H1b, M, 2048, 256, 1);

    // 14. FFN down (K=2048) + residual(bufD) -> bufC; 15. LN3 -> d_out
    gemm3_kernel<u16, float><<<dim3(2, GY), 256, 0, stream>>>(H1b, Wb + WOFF_FFN2, Bb + BOFF_FFN2, bufD, bufC, M, 256, 2048, 0);
    ln_kernel<<<3600, 256, 0, stream>>>(bufC, ln3_g, ln3_b, (float*)d_out, nullptr, M);
}

// Round 10
// 965.547 us; speedup vs baseline: 1.4525x; 1.1337x over previous
//
#include <hip/hip_runtime.h>
#include <hip/hip_bf16.h>
#include <math.h>

#define B_    16
#define LQ_   900
#define D_    256
#define NH_   8
#define HD_   32
#define NL_   4
#define NP_   4
#define DFFN_ 2048
#define LIN_  21760

typedef unsigned short u16;
typedef __attribute__((ext_vector_type(8))) short bf16x8;
typedef __attribute__((ext_vector_type(4))) float f32x4;

__device__ __forceinline__ short f2bf(float f) {
    unsigned u = __float_as_uint(f);
    u += 0x7fffu + ((u >> 16) & 1u);   // RNE
    return (short)(u >> 16);
}
__device__ __forceinline__ float bf2f(u16 u) {
    return __uint_as_float(((unsigned)u) << 16);
}

// ---------------------------------------------------------------------------
// weight prep: fp32 weights -> bf16 Wb (samp & attw ADJACENT for N=384 fusion)
// ---------------------------------------------------------------------------
#define WOFF_INPROJ  0
#define WOFF_OUTPROJ 196608
#define WOFF_VALPROJ 262144
#define WOFF_SAMP    327680
#define WOFF_ATTW    393216
#define WOFF_MSOUT   425984
#define WOFF_FFN1    491520
#define WOFF_FFN2    1015808
#define WTOTAL       1540096

__global__ __launch_bounds__(256) void wprep_kernel(const float* __restrict__ s0,
                                                    const float* __restrict__ s1,
                                                    const float* __restrict__ s2,
                                                    const float* __restrict__ s3,
                                                    const float* __restrict__ s4,
                                                    const float* __restrict__ s5,
                                                    const float* __restrict__ s6,
                                                    const float* __restrict__ s7,
                                                    u16* __restrict__ Wb) {
    int i8 = (blockIdx.x * 256 + threadIdx.x) * 8;
    if (i8 >= WTOTAL) return;
    const float* src; int rel;
    if      (i8 < WOFF_OUTPROJ) { src = s0; rel = i8; }
    else if (i8 < WOFF_VALPROJ) { src = s1; rel = i8 - WOFF_OUTPROJ; }
    else if (i8 < WOFF_SAMP)    { src = s2; rel = i8 - WOFF_VALPROJ; }
    else if (i8 < WOFF_ATTW)    { src = s3; rel = i8 - WOFF_SAMP; }
    else if (i8 < WOFF_MSOUT)   { src = s4; rel = i8 - WOFF_ATTW; }
    else if (i8 < WOFF_FFN1)    { src = s5; rel = i8 - WOFF_MSOUT; }
    else if (i8 < WOFF_FFN2)    { src = s6; rel = i8 - WOFF_FFN1; }
    else                        { src = s7; rel = i8 - WOFF_FFN2; }
    float4 v0 = *(const float4*)(src + rel);
    float4 v1 = *(const float4*)(src + rel + 4);
    short o[8];
    o[0] = f2bf(v0.x); o[1] = f2bf(v0.y); o[2] = f2bf(v0.z); o[3] = f2bf(v0.w);
    o[4] = f2bf(v1.x); o[5] = f2bf(v1.y); o[6] = f2bf(v1.z); o[7] = f2bf(v1.w);
    *(bf16x8*)(Wb + i8) = *(bf16x8*)o;
}

// bias concat (f32)
#define BOFF_INPROJ  0
#define BOFF_OUTPROJ 768
#define BOFF_VALPROJ 1024
#define BOFF_SAMPATT 1280
#define BOFF_MSOUT   1664
#define BOFF_FFN1    1920
#define BOFF_FFN2    3968
#define BTOTAL       4224

__global__ __launch_bounds__(256) void bprep_kernel(const float* __restrict__ b0,
                                                    const float* __restrict__ b1,
                                                    const float* __restrict__ b2,
                                                    const float* __restrict__ b3,
                                                    const float* __restrict__ b4,
                                                    const float* __restrict__ b5,
                                                    const float* __restrict__ b6,
                                                    const float* __restrict__ b7,
                                                    float* __restrict__ Bb) {
    int i = blockIdx.x * 256 + threadIdx.x;
    if (i >= BTOTAL) return;
    const float* s; int rel;
    if      (i < BOFF_OUTPROJ) { s = b0; rel = i; }
    else if (i < BOFF_VALPROJ) { s = b1; rel = i - BOFF_OUTPROJ; }
    else if (i < BOFF_SAMPATT) { s = b2; rel = i - BOFF_VALPROJ; }
    else if (i < 1536)         { s = b3; rel = i - BOFF_SAMPATT; }
    else if (i < BOFF_MSOUT)   { s = b4; rel = i - 1536; }
    else if (i < BOFF_FFN1)    { s = b5; rel = i - BOFF_MSOUT; }
    else if (i < BOFF_FFN2)    { s = b6; rel = i - BOFF_FFN1; }
    else                       { s = b7; rel = i - BOFF_FFN2; }
    Bb[i] = s[rel];
}

// ---------------------------------------------------------------------------
// fused add -> bf16 (and optional bf16 copy of input a)
// ---------------------------------------------------------------------------
__global__ __launch_bounds__(256) void add_bf16_kernel(const float* __restrict__ a,
                                                       const float* __restrict__ b,
                                                       u16* __restrict__ osum,
                                                       u16* __restrict__ oa,
                                                       size_t n4) {
    size_t i = (size_t)blockIdx.x * blockDim.x + threadIdx.x;
    if (i >= n4) return;
    float4 x = ((const float4*)a)[i];
    float4 y = ((const float4*)b)[i];
    ushort4 s;
    s.x = (u16)f2bf(x.x + y.x); s.y = (u16)f2bf(x.y + y.y);
    s.z = (u16)f2bf(x.z + y.z); s.w = (u16)f2bf(x.w + y.w);
    ((ushort4*)osum)[i] = s;
    if (oa) {
        ushort4 q;
        q.x = (u16)f2bf(x.x); q.y = (u16)f2bf(x.y);
        q.z = (u16)f2bf(x.z); q.w = (u16)f2bf(x.w);
        ((ushort4*)oa)[i] = q;
    }
}

// ---------------------------------------------------------------------------
// gemm4: 512-thread (8-wave) pipelined bf16 MFMA GEMM, occupancy-optimized.
// C[M,N] = A[M,K] @ W[N,K]^T + bias (+res f32)(+relu). W pre-converted bf16.
// 128x128 tile, BK=32, wave grid 2x4 (each wave 64 rows x 32 cols, acc=32 AGPR),
// 1-deep register prefetch (round-6-proven), double-buffered LDS, one barrier
// per K-step. Staging: 1 b128 per array per thread (row t>>2, col (t&3)*8).
// ---------------------------------------------------------------------------
#define LDK 40
template <typename TA, typename TC>
__global__ __launch_bounds__(512) void gemm4_kernel(const TA* __restrict__ A,
                                                    const u16* __restrict__ W,
                                                    const float* __restrict__ bias,
                                                    const float* __restrict__ res,
                                                    TC* __restrict__ C,
                                                    int M, int N, int K, int relu) {
    __shared__ __align__(16) u16 As[2][128 * LDK];
    __shared__ __align__(16) u16 Bs[2][128 * LDK];

    const int n0 = blockIdx.x * 128;
    const int m0 = blockIdx.y * 128;
    const int t  = threadIdx.x;
    const int srow = t >> 2;          // 0..127
    const int scol = (t & 3) << 3;    // 0,8,16,24
    const int lane = t & 63;
    const int lr   = lane & 15;
    const int kg   = lane >> 4;
    const int wid  = t >> 6;          // 0..7
    const int wr   = wid >> 2;        // 0..1 (64-row stripe)
    const int wc   = wid & 3;         // 0..3 (32-col stripe)

    f32x4 acc[4][2] = {};

    const int  nk  = K >> 5;
    const int  gm  = m0 + srow;
    const bool mok = (gm < M);

    const float* af32 = (const float*)A + (size_t)(mok ? gm : 0) * K + scol;
    const u16*   ab16 = (const u16*)A + (size_t)(mok ? gm : 0) * K + scol;
    const u16*   wp   = W + (size_t)(n0 + srow) * K + scol;

    float4 af[2];
    bf16x8 ab;
    bf16x8 wf;
    if (!mok) {
        af[0] = af[1] = make_float4(0.f, 0.f, 0.f, 0.f);
        #pragma unroll
        for (int q = 0; q < 8; ++q) ab[q] = 0;
    }

    // prologue: load k-step 0
    if constexpr (sizeof(TA) == 4) {
        if (mok) { af[0] = *(const float4*)af32; af[1] = *(const float4*)(af32 + 4); }
    } else {
        if (mok) ab = *(const bf16x8*)ab16;
    }
    wf = *(const bf16x8*)wp;

    for (int kt = 0; kt < nk; ++kt) {
        const int cur = kt & 1;
        // ---- ds_write staged regs -> buf[cur] ----
        if constexpr (sizeof(TA) == 4) {
            short tmp[8];
            tmp[0] = f2bf(af[0].x); tmp[1] = f2bf(af[0].y);
            tmp[2] = f2bf(af[0].z); tmp[3] = f2bf(af[0].w);
            tmp[4] = f2bf(af[1].x); tmp[5] = f2bf(af[1].y);
            tmp[6] = f2bf(af[1].z); tmp[7] = f2bf(af[1].w);
            *(bf16x8*)&As[cur][srow * LDK + scol] = *(bf16x8*)tmp;
        } else {
            *(bf16x8*)&As[cur][srow * LDK + scol] = ab;
        }
        *(bf16x8*)&Bs[cur][srow * LDK + scol] = wf;

        // ---- prefetch k-step kt+1 into regs ----
        if (kt + 1 < nk) {
            const int k1 = (kt + 1) << 5;
            if constexpr (sizeof(TA) == 4) {
                if (mok) { af[0] = *(const float4*)(af32 + k1); af[1] = *(const float4*)(af32 + k1 + 4); }
            } else {
                if (mok) ab = *(const bf16x8*)(ab16 + k1);
            }
            wf = *(const bf16x8*)(wp + k1);
        }

        __syncthreads();

        // ---- MFMA from buf[cur]: wave tile 64x32 ----
        const u16* pA = &As[cur][(wr * 64 + lr) * LDK + kg * 8];
        const u16* pB = &Bs[cur][(wc * 32 + lr) * LDK + kg * 8];
        bf16x8 a[4], b[2];
        #pragma unroll
        for (int i = 0; i < 4; ++i) a[i] = *(const bf16x8*)(pA + i * 16 * LDK);
        #pragma unroll
        for (int j = 0; j < 2; ++j) b[j] = *(const bf16x8*)(pB + j * 16 * LDK);
        #pragma unroll
        for (int i = 0; i < 4; ++i)
            #pragma unroll
            for (int j = 0; j < 2; ++j)
                acc[i][j] = __builtin_amdgcn_mfma_f32_16x16x32_bf16(a[i], b[j], acc[i][j], 0, 0, 0);
    }

    // epilogue: D row = kg*4 + r, col = lr (m89-verified)
    #pragma unroll
    for (int i = 0; i < 4; ++i) {
        #pragma unroll
        for (int j = 0; j < 2; ++j) {
            const int n = n0 + wc * 32 + j * 16 + lr;
            const float bn = bias[n];
            #pragma unroll
            for (int r = 0; r < 4; ++r) {
                const int m = m0 + wr * 64 + i * 16 + kg * 4 + r;
                if (m < M) {
                    float v = acc[i][j][r] + bn;
                    if (res)  v += res[(size_t)m * N + n];
                    if (relu) v = fmaxf(v, 0.f);
                    if constexpr (sizeof(TC) == 4) C[(size_t)m * N + n] = v;
                    else                           C[(size_t)m * N + n] = (TC)(u16)f2bf(v);
                }
            }
        }
    }
}

// ---------------------------------------------------------------------------
// MFMA flash attention. QK fused layout: row stride 512 (Q at +0, K at +256);
// V separate, stride 256. (verified rounds 7/8)
// ---------------------------------------------------------------------------
#define LDA2 40
#define LDP  72
__global__ __launch_bounds__(256) void attn_mfma_kernel(const u16* __restrict__ QKg,
                                                        const u16* __restrict__ Vg,
                                                        u16* __restrict__ Og) {
    __shared__ __align__(16) u16 Ks[64 * LDA2];
    __shared__ __align__(16) u16 Vs[64 * LDA2];
    __shared__ __align__(16) u16 Ps[4][16 * LDP];

    const int qt = blockIdx.x, h = blockIdx.y, b = blockIdx.z;
    const int t  = threadIdx.x;
    const int wq = t >> 6;
    const int lane = t & 63;
    const int l15  = lane & 15;
    const int g    = lane >> 4;
    const int q0   = qt * 64;

    const int srow = t >> 2;
    const int sd   = (t & 3) * 8;

    int qrow = q0 + wq * 16 + l15;
    if (qrow > LQ_ - 1) qrow = LQ_ - 1;
    const bf16x8 qfrag = *(const bf16x8*)(QKg + ((size_t)(b * LQ_) + qrow) * 512 + h * HD_ + g * 8);

    float m_i = -1e30f, l_i = 0.f;
    f32x4 o_acc[2] = {};
    const float scale = 0.17677669529663687f;

    for (int k0 = 0; k0 < 960; k0 += 64) {
        {
            int kr = k0 + srow;
            bf16x8 kv, vv;
            if (kr < LQ_) {
                kv = *(const bf16x8*)(QKg + ((size_t)(b * LQ_) + kr) * 512 + 256 + h * HD_ + sd);
                vv = *(const bf16x8*)(Vg + ((size_t)(b * LQ_) + kr) * D_ + h * HD_ + sd);
            } else {
                #pragma unroll
                for (int j = 0; j < 8; ++j) { kv[j] = 0; vv[j] = 0; }
            }
            *(bf16x8*)&Ks[srow * LDA2 + sd] = kv;
            *(bf16x8*)&Vs[srow * LDA2 + sd] = vv;
        }
        __syncthreads();

        float p[4][4];
        float tmax = -1e30f;
        #pragma unroll
        for (int kt = 0; kt < 4; ++kt) {
            bf16x8 af = *(const bf16x8*)&Ks[(kt * 16 + l15) * LDA2 + g * 8];
            f32x4 c = {0.f, 0.f, 0.f, 0.f};
            c = __builtin_amdgcn_mfma_f32_16x16x32_bf16(af, qfrag, c, 0, 0, 0);
            #pragma unroll
            for (int r = 0; r < 4; ++r) {
                int kglob = k0 + kt * 16 + g * 4 + r;
                float s = (kglob < LQ_) ? c[r] * scale : -1e30f;
                p[kt][r] = s;
                tmax = fmaxf(tmax, s);
            }
        }
        tmax = fmaxf(tmax, __shfl_xor(tmax, 16));
        tmax = fmaxf(tmax, __shfl_xor(tmax, 32));
        float newm = fmaxf(m_i, tmax);
        float corr = __expf(m_i - newm);
        float rs = 0.f;
        #pragma unroll
        for (int kt = 0; kt < 4; ++kt) {
            #pragma unroll
            for (int r = 0; r < 4; ++r) {
                float e = __expf(p[kt][r] - newm);
                p[kt][r] = e;
                rs += e;
            }
            ushort4 pk;
            pk.x = (u16)f2bf(p[kt][0]);
            pk.y = (u16)f2bf(p[kt][1]);
            pk.z = (u16)f2bf(p[kt][2]);
            pk.w = (u16)f2bf(p[kt][3]);
            *(ushort4*)&Ps[wq][l15 * LDP + kt * 16 + g * 4] = pk;
        }
        rs += __shfl_xor(rs, 16);
        rs += __shfl_xor(rs, 32);
        l_i = l_i * corr + rs;
        m_i = newm;

        #pragma unroll
        for (int r = 0; r < 4; ++r) {
            float cq = __shfl(corr, g * 4 + r);
            o_acc[0][r] *= cq;
            o_acc[1][r] *= cq;
        }

        #pragma unroll
        for (int c = 0; c < 2; ++c) {
            bf16x8 pa = *(const bf16x8*)&Ps[wq][l15 * LDP + c * 32 + g * 8];
            #pragma unroll
            for (int nt = 0; nt < 2; ++nt) {
                short vv[8];
                #pragma unroll
                for (int j = 0; j < 8; ++j)
                    vv[j] = (short)Vs[(c * 32 + g * 8 + j) * LDA2 + nt * 16 + l15];
                o_acc[nt] = __builtin_amdgcn_mfma_f32_16x16x32_bf16(pa, *(bf16x8*)vv, o_acc[nt], 0, 0, 0);
            }
        }
        __syncthreads();
    }

    float il = 1.f / l_i;
    #pragma unroll
    for (int r = 0; r < 4; ++r) {
        float ilq = __shfl(il, g * 4 + r);
        int q = q0 + wq * 16 + g * 4 + r;
        if (q < LQ_) {
            u16* dst = Og + ((size_t)(b * LQ_) + q) * D_ + h * HD_ + l15;
            dst[0]  = (u16)f2bf(o_acc[0][r] * ilq);
            dst[16] = (u16)f2bf(o_acc[1][r] * ilq);
        }
    }
}

// ---------------------------------------------------------------------------
// LayerNorm over D=256; optional bf16 second output
// ---------------------------------------------------------------------------
__global__ __launch_bounds__(256) void ln_kernel(const float* __restrict__ X,
                                                 const float* __restrict__ g,
                                                 const float* __restrict__ bb,
                                                 float* __restrict__ Y,
                                                 u16* __restrict__ Yb, int M) {
    int row  = blockIdx.x * 4 + (threadIdx.x >> 6);
    int lane = threadIdx.x & 63;
    if (row >= M) return;
    const float* x = X + (size_t)row * D_;
    float4 v = *(const float4*)(x + lane * 4);
    float s = v.x + v.y + v.z + v.w;
    #pragma unroll
    for (int o = 32; o >= 1; o >>= 1) s += __shfl_xor(s, o);
    float mean = s * (1.f / D_);
    float dx0 = v.x - mean, dx1 = v.y - mean, dx2 = v.z - mean, dx3 = v.w - mean;
    float ss = dx0 * dx0 + dx1 * dx1 + dx2 * dx2 + dx3 * dx3;
    #pragma unroll
    for (int o = 32; o >= 1; o >>= 1) ss += __shfl_xor(ss, o);
    float rstd = rsqrtf(ss * (1.f / D_) + 1e-5f);
    float4 gv = *(const float4*)(g + lane * 4);
    float4 bv = *(const float4*)(bb + lane * 4);
    float4 out;
    out.x = dx0 * rstd * gv.x + bv.x;
    out.y = dx1 * rstd * gv.y + bv.y;
    out.z = dx2 * rstd * gv.z + bv.z;
    out.w = dx3 * rstd * gv.w + bv.w;
    *(float4*)(Y + (size_t)row * D_ + lane * 4) = out;
    if (Yb) {
        ushort4 ob;
        ob.x = (u16)f2bf(out.x); ob.y = (u16)f2bf(out.y);
        ob.z = (u16)f2bf(out.z); ob.w = (u16)f2bf(out.w);
        *(ushort4*)(Yb + (size_t)row * D_ + lane * 4) = ob;
    }
}

// ---------------------------------------------------------------------------
// softmax over 16: logits in fused (M,384) buffer at col 256 + h*16
// ---------------------------------------------------------------------------
__global__ __launch_bounds__(256) void softmax16v_kernel(const float* __restrict__ X,
                                                         float* __restrict__ Y,
                                                         int rows) {
    int r = blockIdx.x * blockDim.x + threadIdx.x;
    if (r >= rows) return;
    const float* x = X + (size_t)(r >> 3) * 384 + 256 + (r & 7) * 16;
    float m = -1e30f;
    #pragma unroll
    for (int i = 0; i < 16; ++i) m = fmaxf(m, x[i]);
    float e[16], s = 0.f;
    #pragma unroll
    for (int i = 0; i < 16; ++i) { e[i] = expf(x[i] - m); s += e[i]; }
    float inv = 1.f / s;
    float* y = Y + (size_t)r * 16;
    #pragma unroll
    for (int i = 0; i < 16; ++i) y[i] = e[i] * inv;
}

// ---------------------------------------------------------------------------
// multi-scale deformable sampling: thread = (b,q,h, 8-dim slice); bf16 value;
// offsets from the fused (M,384) buffer (cols 0..255). (verified rounds 7/8)
// ---------------------------------------------------------------------------
__global__ __launch_bounds__(256) void msdeform2_kernel(const u16* __restrict__ value,
                                                        const float* __restrict__ ref,
                                                        const float* __restrict__ off,
                                                        const float* __restrict__ attw,
                                                        u16* __restrict__ out) {
    const int levH[4] = {128, 64, 32, 16};
    const int levW[4] = {128, 64, 32, 16};
    const int levS[4] = {0, 16384, 20480, 21504};

    int gid = blockIdx.x * 256 + threadIdx.x;     // B*LQ*NH*4 = 460800
    int d8  = gid & 3;
    int bqh = gid >> 2;
    int h   = bqh & (NH_ - 1);
    int bq  = bqh >> 3;
    int b   = bq / LQ_;

    const float* refp = ref  + (size_t)bq * NL_ * 2;
    const float* offp = off  + (size_t)bq * 384 + h * 32;
    const float* awp  = attw + (size_t)bq * 128 + h * 16;
    const u16* vbase  = value + (size_t)b * LIN_ * D_ + h * HD_ + d8 * 8;

    float acc[8] = {};
    #pragma unroll
    for (int l = 0; l < NL_; ++l) {
        float rx = refp[l * 2 + 0], ry = refp[l * 2 + 1];
        const int wl = levW[l], hl = levH[l];
        const u16* vlev = vbase + (size_t)levS[l] * D_;
        #pragma unroll
        for (int p = 0; p < NP_; ++p) {
            float ox = offp[(l * NP_ + p) * 2 + 0];
            float oy = offp[(l * NP_ + p) * 2 + 1];
            float x = rx * wl + ox - 0.5f;
            float y = ry * hl + oy - 0.5f;
            float x0f = floorf(x), y0f = floorf(y);
            float fx = x - x0f, fy = y - y0f;
            int x0 = (int)x0f, y0 = (int)y0f;
            float aw = awp[l * NP_ + p];
            #pragma unroll
            for (int dy = 0; dy < 2; ++dy) {
                int   yi = y0 + dy;
                float wy = dy ? fy : 1.f - fy;
                bool  vy = (yi >= 0) && (yi < hl);
                int   yc = min(max(yi, 0), hl - 1);
                #pragma unroll
                for (int dx = 0; dx < 2; ++dx) {
                    int   xi = x0 + dx;
                    float wx = dx ? fx : 1.f - fx;
                    bool  vx = (xi >= 0) && (xi < wl);
                    int   xc = min(max(xi, 0), wl - 1);
                    float w  = (vx && vy) ? aw * wy * wx : 0.f;
                    bf16x8 v = *(const bf16x8*)(vlev + (size_t)(yc * wl + xc) * D_);
                    #pragma unroll
                    for (int j = 0; j < 8; ++j)
                        acc[j] += w * bf2f((u16)v[j]);
                }
            }
        }
    }
    short o[8];
    #pragma unroll
    for (int j = 0; j < 8; ++j) o[j] = f2bf(acc[j]);
    *(bf16x8*)(out + (size_t)bq * D_ + h * HD_ + d8 * 8) = *(bf16x8*)o;
}

// ---------------------------------------------------------------------------
extern "C" void kernel_launch(void* const* d_in, const int* in_sizes, int n_in,
                              void* d_out, int out_size, void* d_ws, size_t ws_size,
                              hipStream_t stream) {
    const float* queries      = (const float*)d_in[0];
    const float* features     = (const float*)d_in[1];
    const float* refpts       = (const float*)d_in[2];
    const float* q_pos        = (const float*)d_in[3];
    const float* in_proj_w    = (const float*)d_in[4];
    const float* in_proj_b    = (const float*)d_in[5];
    const float* out_proj_w   = (const float*)d_in[6];
    const float* out_proj_b   = (const float*)d_in[7];
    const float* value_proj_w = (const float*)d_in[8];
    const float* value_proj_b = (const float*)d_in[9];
    const float* samp_w       = (const float*)d_in[10];
    const float* samp_b       = (const float*)d_in[11];
    const float* attw_w       = (const float*)d_in[12];
    const float* attw_b       = (const float*)d_in[13];
    const float* msout_w      = (const float*)d_in[14];
    const float* msout_b      = (const float*)d_in[15];
    const float* ffn_w1       = (const float*)d_in[16];
    const float* ffn_b1       = (const float*)d_in[17];
    const float* ffn_w2       = (const float*)d_in[18];
    const float* ffn_b2       = (const float*)d_in[19];
    const float* ln1_g        = (const float*)d_in[20];
    const float* ln1_b        = (const float*)d_in[21];
    const float* ln2_g        = (const float*)d_in[22];
    const float* ln2_b        = (const float*)d_in[23];
    const float* ln3_g        = (const float*)d_in[24];
    const float* ln3_b        = (const float*)d_in[25];

    float* ws = (float*)d_ws;
    const size_t NQ = (size_t)B_ * LQ_ * D_;          // 3,686,400
    // f32 scratch
    float* bufB = ws;                                  // (M,384) samp+attw logits
    float* bufC = ws + 3 * NQ / 2;                     // (M,256) pre-LN / post-FFN2
    float* bufF = bufC + NQ;                           // x (post-LN1)
    float* bufD = bufF + NQ;                           // attw softmax; later LN2 f32
    // bf16 scratch
    u16* U    = (u16*)(bufD + NQ);
    u16* qkb  = U;                                     // bf16(queries+q_pos)
    u16* qb   = U + NQ;                                // bf16(queries)
    u16* q2b  = U + 2 * NQ;                            // bf16(x+q_pos)
    u16* QKb  = U + 3 * NQ;                            // (M,512) fused Q|K
    u16* Vb   = U + 5 * NQ;
    u16* Ob   = U + 6 * NQ;
    u16* MSb  = U + 7 * NQ;
    u16* LN2b = U + 8 * NQ;
    u16* VALb = U + 9 * NQ;                            // (B, LIN, 256)
    u16* H1b  = VALb + (size_t)B_ * LIN_ * D_;         // (M, 2048)
    u16* Wb   = H1b + (size_t)B_ * LQ_ * DFFN_;        // all weights bf16
    float* Bb = (float*)(Wb + WTOTAL);                 // concat biases f32

    const int M = B_ * LQ_;           // 14400
    const int GY = 113;               // ceil(14400/128)

    // 0. weight + bias prep
    wprep_kernel<<<752, 256, 0, stream>>>(in_proj_w, out_proj_w, value_proj_w, samp_w,
                                          attw_w, msout_w, ffn_w1, ffn_w2, Wb);
    bprep_kernel<<<17, 256, 0, stream>>>(in_proj_b, out_proj_b, value_proj_b, samp_b,
                                         attw_b, msout_b, ffn_b1, ffn_b2, Bb);

    // 1. qkb = bf16(queries + q_pos); qb = bf16(queries)
    add_bf16_kernel<<<3600, 256, 0, stream>>>(queries, q_pos, qkb, qb, NQ / 4);

    // 2. fused Q|K (N=512) and V (N=256)
    gemm4_kernel<u16, u16><<<dim3(4, GY), 512, 0, stream>>>(qkb, Wb + WOFF_INPROJ, Bb + BOFF_INPROJ, nullptr, QKb, M, 512, 256, 0);
    gemm4_kernel<u16, u16><<<dim3(2, GY), 512, 0, stream>>>(qb, Wb + WOFF_INPROJ + 131072, Bb + BOFF_INPROJ + 512, nullptr, Vb, M, 256, 256, 0);

    // 3. attention -> Ob
    attn_mfma_kernel<<<dim3(15, NH_, B_), 256, 0, stream>>>(QKb, Vb, Ob);

    // 4. out-proj + residual(queries) -> bufC; 5. LN1 -> bufF
    gemm4_kernel<u16, float><<<dim3(2, GY), 512, 0, stream>>>(Ob, Wb + WOFF_OUTPROJ, Bb + BOFF_OUTPROJ, queries, bufC, M, 256, 256, 0);
    ln_kernel<<<3600, 256, 0, stream>>>(bufC, ln1_g, ln1_b, bufF, nullptr, M);

    // 6. q2b = bf16(x + q_pos)
    add_bf16_kernel<<<3600, 256, 0, stream>>>(bufF, q_pos, q2b, nullptr, NQ / 4);

    // 7. value projection (f32 A, pipelined conversion) -> VALb
    gemm4_kernel<float, u16><<<dim3(2, 2720), 512, 0, stream>>>(features, Wb + WOFF_VALPROJ, Bb + BOFF_VALPROJ, nullptr, VALb, B_ * LIN_, 256, 256, 0);

    // 8. fused samp+attw (N=384) -> bufB
    gemm4_kernel<u16, float><<<dim3(3, GY), 512, 0, stream>>>(q2b, Wb + WOFF_SAMP, Bb + BOFF_SAMPATT, nullptr, bufB, M, 384, 256, 0);

    // 9. softmax over 16 -> bufD
    softmax16v_kernel<<<450, 256, 0, stream>>>(bufB, bufD, B_ * LQ_ * NH_);

    // 10. deformable sampling -> MSb
    msdeform2_kernel<<<1800, 256, 0, stream>>>(VALb, refpts, bufB, bufD, MSb);

    // 11. msout + residual(bufF) -> bufC; 12. LN2 -> bufD(f32) + LN2b(bf16)
    gemm4_kernel<u16, float><<<dim3(2, GY), 512, 0, stream>>>(MSb, Wb + WOFF_MSOUT, Bb + BOFF_MSOUT, bufF, bufC, M, 256, 256, 0);
    ln_kernel<<<3600, 256, 0, stream>>>(bufC, ln2_g, ln2_b, bufD, LN2b, M);

    // 13. FFN up + ReLU (N=2048) -> H1b
    gemm4_kernel<u16, u16><<<dim3(16, GY), 512, 0, stream>>>(LN2b, Wb + WOFF_FFN1, Bb + BOFF_FFN1, nullptr, H1b, M, 2048, 256, 1);

    // 14. FFN down (K=2048) + residual(bufD) -> bufC; 15. LN3 -> d_out
    gemm4_kernel<u16, float><<<dim3(2, GY), 512, 0, stream>>>(H1b, Wb + WOFF_FFN2, Bb + BOFF_FFN2, bufD, bufC, M, 256, 2048, 0);
    ln_kernel<<<3600, 256, 0, stream>>>(bufC, ln3_g, ln3_b, (float*)d_out, nullptr, M);
}